// Round 1
// baseline (77.971 us; speedup 1.0000x reference)
//
#include <hip/hip_runtime.h>
#include <math.h>

#define ALPHA_C 0.3f
#define BETA_C  0.4f
#define ETA_C   0.3f
#define TT 8192
#define FF 64
#define TILE 32
#define NW 4

__device__ __forceinline__ float rcpf(float x) { return __builtin_amdgcn_rcpf(x); }

// ---------------- prep: softmax rows of W (transposed out), transpose proj_w ----------------
__global__ void prep_kernel(const float* __restrict__ W,
                            const float* __restrict__ PW,
                            float* __restrict__ wT,
                            float* __restrict__ pwT) {
    const int lane = threadIdx.x;   // 0..63  (column j)
    const int wv   = threadIdx.y;   // 0..3
    for (int it = 0; it < 16; ++it) {
        const int r = wv * 16 + it; // row i
        float v = W[r * 64 + lane];
        float m = v;
        #pragma unroll
        for (int off = 32; off >= 1; off >>= 1)
            m = fmaxf(m, __shfl_xor(m, off, 64));
        float e = __expf(v - m);
        float s = e;
        #pragma unroll
        for (int off = 32; off >= 1; off >>= 1)
            s += __shfl_xor(s, off, 64);
        wT[lane * 64 + r]  = e * rcpf(s);          // wT[j][i] = softmax(W)[i][j]
        pwT[lane * 64 + r] = PW[r * 64 + lane];    // pwT[f][i] = proj_w[i][f]
    }
}

// ---------------- fused main kernel ----------------
__global__ __launch_bounds__(256, 4)
void mcao_main(const float* __restrict__ x,
               const float* __restrict__ wT,
               const float* __restrict__ pwT,
               const float* __restrict__ pb,
               const float* __restrict__ kap,
               const float* __restrict__ coeffs,
               float* __restrict__ out,
               float* __restrict__ memout) {
    __shared__ float  xs[(TILE + 50) * 64];     // 20992 B
    __shared__ float  pw_lds[64 * 64];          // 16384 B
    __shared__ float4 tux[NW][64];              //  4096 B

    const int tid  = threadIdx.x;
    const int lane = tid & 63;
    const int wv   = tid >> 6;

    const int tilesPerB = TT / TILE;            // 256
    const int b  = blockIdx.x / tilesPerB;
    const int t0 = (blockIdx.x % tilesPerB) * TILE;

    const float* xb = x + (size_t)b * TT * FF;

    // stage x rows [t0-50, t0+TILE) into LDS (zero-pad t<0)
    {
        const int total4 = (TILE + 50) * 64 / 4;   // 1312 float4
        for (int i4 = tid; i4 < total4; i4 += 256) {
            const int e0 = i4 * 4;
            const int s  = e0 >> 6;
            const int f  = e0 & 63;
            const int t  = t0 - 50 + s;
            float4 v = make_float4(0.f, 0.f, 0.f, 0.f);
            if (t >= 0) v = *reinterpret_cast<const float4*>(xb + t * 64 + f);
            *reinterpret_cast<float4*>(&xs[e0]) = v;
        }
        for (int i4 = tid; i4 < 1024; i4 += 256)
            reinterpret_cast<float4*>(pw_lds)[i4] =
                reinterpret_cast<const float4*>(pwT)[i4];
    }

    // softmaxed W row for this lane: wreg[j] = w[lane][j]
    float wreg[64];
    #pragma unroll
    for (int j = 0; j < 64; ++j) wreg[j] = wT[j * 64 + lane];

    __syncthreads();

    // ---- FIR phase: this wave owns local rows [8*wv, 8*wv+8) ----
    float macc[8];
    #pragma unroll
    for (int r = 0; r < 8; ++r) macc[r] = 0.f;
    {
        const int base = 8 * wv;
        #pragma unroll
        for (int s = 0; s < 58; ++s) {
            const float xv = xs[(base + s) * 64 + lane];
            #pragma unroll
            for (int r = 0; r < 8; ++r) {
                const int k = 50 + r - s;
                if (0 <= k && k <= 50)
                    macc[r] = fmaf(coeffs[k], xv, macc[r]);
            }
        }
    }

    const float kappa  = kap[0];
    const float inv1mr = rcpf(1.f - __expf(-kappa));
    const float pbias  = pb[lane];

    // ---- per-row coupling + proj + combine ----
    #pragma unroll 1
    for (int r = 0; r < 8; ++r) {
        const int   lt = 8 * wv + r;
        const float xi = xs[(lt + 50) * 64 + lane];
        const float E  = __expf(2.f * xi);
        const float ti = fmaf(-2.f, rcpf(E + 1.f), 1.f);   // tanh(xi)
        const float ui = __expf(-fabsf(xi));               // e^{-|xi|}
        tux[wv][lane] = make_float4(ti, ui, xi, 0.f);

        float cacc = 0.f, pacc = 0.f;
        #pragma unroll
        for (int j = 0; j < 64; ++j) {
            const float4 v  = tux[wv][j];                  // broadcast {t_j,u_j,x_j}
            const float d1  = fmaf(-ti, v.x, 1.f);         // 1 - ti*tj
            const float d2  = fmaf(ui, v.y, 1.f);          // 1 + ui*uj
            const float num = ti - v.x;
            const float rr  = rcpf(d1 * d2);
            cacc = fmaf(num * wreg[j], rr, cacc);
            pacc = fmaf(v.z, pw_lds[j * 64 + lane], pacc); // proj
        }

        const int   t    = t0 + lt;
        const float ksum = (1.f - __expf(-kappa * (float)(t + 1))) * inv1mr;
        const float proj = pacc + pbias;
        const float m    = macc[r];
        const size_t o   = (size_t)(b * TT + t) * 64 + lane;
        out[o]    = ALPHA_C * m + BETA_C * cacc + ETA_C * proj * ksum;
        memout[o] = m;
    }
}

extern "C" void kernel_launch(void* const* d_in, const int* in_sizes, int n_in,
                              void* d_out, int out_size, void* d_ws, size_t ws_size,
                              hipStream_t stream) {
    const float* x   = (const float*)d_in[0];
    const float* W   = (const float*)d_in[1];
    const float* PW  = (const float*)d_in[2];
    const float* pb  = (const float*)d_in[3];
    const float* kap = (const float*)d_in[4];
    const float* cf  = (const float*)d_in[5];

    float* out    = (float*)d_out;
    float* memout = out + (size_t)4 * TT * FF;

    float* wT  = (float*)d_ws;
    float* pwT = wT + 64 * 64;

    hipLaunchKernelGGL(prep_kernel, dim3(1), dim3(64, 4), 0, stream, W, PW, wT, pwT);

    const int nblocks = 4 * (TT / TILE);   // 1024
    hipLaunchKernelGGL(mcao_main, dim3(nblocks), dim3(256), 0, stream,
                       x, wT, pwT, pb, kap, cf, out, memout);
}

// Round 2
// 63.208 us; speedup vs baseline: 1.2336x; 1.2336x over previous
//
#include <hip/hip_runtime.h>
#include <hip/hip_fp16.h>
#include <math.h>

#define TT 8192
#define FF 64
#define TILE 16
#define NW 4

__device__ __forceinline__ float rcpf(float x) { return __builtin_amdgcn_rcpf(x); }

// ---- prep: softmax rows of W; pack {softmax_w[i][j], proj_w[i][j]} as half2 at wp[j*64+i] ----
__global__ void prep_kernel(const float* __restrict__ W,
                            const float* __restrict__ PW,
                            __half2* __restrict__ wp) {
    const int lane = threadIdx.x;   // j
    const int wv   = threadIdx.y;   // 0..3
    for (int it = 0; it < 16; ++it) {
        const int r = wv * 16 + it; // i
        float v = W[r * 64 + lane];
        float m = v;
        #pragma unroll
        for (int off = 32; off >= 1; off >>= 1)
            m = fmaxf(m, __shfl_xor(m, off, 64));
        float e = __expf(v - m);
        float s = e;
        #pragma unroll
        for (int off = 32; off >= 1; off >>= 1)
            s += __shfl_xor(s, off, 64);
        const float w = e * rcpf(s);
        const float p = PW[r * 64 + lane];
        wp[lane * 64 + r] = __floats2half2_rn(w, p);   // wp[j][i]
    }
}

// ---- fused main kernel ----
__global__ __launch_bounds__(256, 5)
void mcao_main(const float* __restrict__ x,
               const __half2* __restrict__ wp,
               const float* __restrict__ pb,
               const float* __restrict__ kap,
               const float* __restrict__ coeffs,
               float* __restrict__ out,
               float* __restrict__ memout) {
    __shared__ float   xs[TILE * 64];       //  4096 B
    __shared__ __half2 wp_lds[64 * 64];     // 16384 B
    __shared__ float2  tu[NW][4][64];       //  8192 B   (total 28672 -> 5 blocks/CU)

    const int tid  = threadIdx.x;
    const int lane = tid & 63;
    const int wv   = tid >> 6;

    const int tilesPerB = TT / TILE;        // 512
    const int b  = blockIdx.x / tilesPerB;
    const int t0 = (blockIdx.x % tilesPerB) * TILE;
    const float* xb = x + (size_t)b * TT * FF;

    // stage xs (16 rows = 256 float4, one per thread) and wp (1024 float4, 4 per thread)
    reinterpret_cast<float4*>(xs)[tid] =
        reinterpret_cast<const float4*>(xb + t0 * 64)[tid];
    #pragma unroll
    for (int k = 0; k < 4; ++k)
        reinterpret_cast<float4*>(wp_lds)[tid + 256 * k] =
            reinterpret_cast<const float4*>(wp)[tid + 256 * k];

    // ---- FIR from global (L2-hot): wave owns rows lt = 4wv..4wv+3 ----
    float macc[4] = {0.f, 0.f, 0.f, 0.f};
    {
        const int tbase = t0 + 4 * wv - 50;   // stream row for s=0
        #pragma unroll
        for (int sc = 0; sc < 7; ++sc) {      // 7 chunks of 8 = 56 >= 54 needed
            float xv[8];
            #pragma unroll
            for (int q = 0; q < 8; ++q) {
                const int s = sc * 8 + q;
                const int t = tbase + s;
                xv[q] = (s < 54 && t >= 0) ? xb[t * 64 + lane] : 0.f;
            }
            #pragma unroll
            for (int q = 0; q < 8; ++q) {
                const int s = sc * 8 + q;
                #pragma unroll
                for (int r = 0; r < 4; ++r) {
                    const int k = 50 + r - s;
                    if (0 <= k && k <= 50)
                        macc[r] = fmaf(coeffs[k], xv[q], macc[r]);
                }
            }
        }
    }

    __syncthreads();

    const float kappa  = kap[0];
    const float inv1mr = rcpf(1.f - __expf(-kappa));
    const float pbias  = pb[lane];

    // per-row feature values for this wave's 4 rows
    float ti[4], ui[4];
    #pragma unroll
    for (int r = 0; r < 4; ++r) {
        const float xi = xs[(4 * wv + r) * 64 + lane];
        const float E  = __expf(2.f * xi);
        ti[r] = fmaf(-2.f, rcpf(E + 1.f), 1.f);   // tanh(xi)
        ui[r] = __expf(-fabsf(xi));               // e^{-|xi|}
        tu[wv][r][lane] = make_float2(ti[r], ui[r]);
    }
    // tu is wave-private: no __syncthreads needed (in-wave LDS ordering)

    float cacc[4] = {0.f, 0.f, 0.f, 0.f};
    float pacc[4] = {0.f, 0.f, 0.f, 0.f};
    #pragma unroll 8
    for (int j = 0; j < 64; ++j) {
        const __half2 wpj = wp_lds[j * 64 + lane];   // conflict-free, lane-contiguous
        const float wj = __low2float(wpj);
        const float pj = __high2float(wpj);
        #pragma unroll
        for (int r = 0; r < 4; ++r) {
            const float2 tj = tu[wv][r][j];           // b64 broadcast
            const float  xj = xs[(4 * wv + r) * 64 + j]; // b32 broadcast
            const float d1  = fmaf(-ti[r], tj.x, 1.f);   // 1 - ti*tj
            const float d2  = fmaf(ui[r], tj.y, 1.f);    // 1 + ui*uj
            const float rrp = rcpf(d1 * d2);
            const float num = ti[r] - tj.x;
            cacc[r] = fmaf(num * wj, rrp, cacc[r]);
            pacc[r] = fmaf(xj, pj, pacc[r]);
        }
    }

    #pragma unroll
    for (int r = 0; r < 4; ++r) {
        const int   t    = t0 + 4 * wv + r;
        const float ksum = (1.f - __expf(-kappa * (float)(t + 1))) * inv1mr;
        const float m    = macc[r];
        const size_t o   = (size_t)(b * TT + t) * 64 + lane;
        out[o]    = 0.3f * m + 0.4f * cacc[r] + 0.3f * (pacc[r] + pbias) * ksum;
        memout[o] = m;
    }
}

extern "C" void kernel_launch(void* const* d_in, const int* in_sizes, int n_in,
                              void* d_out, int out_size, void* d_ws, size_t ws_size,
                              hipStream_t stream) {
    const float* x   = (const float*)d_in[0];
    const float* W   = (const float*)d_in[1];
    const float* PW  = (const float*)d_in[2];
    const float* pb  = (const float*)d_in[3];
    const float* kap = (const float*)d_in[4];
    const float* cf  = (const float*)d_in[5];

    float* out    = (float*)d_out;
    float* memout = out + (size_t)4 * TT * FF;

    __half2* wp = (__half2*)d_ws;

    hipLaunchKernelGGL(prep_kernel, dim3(1), dim3(64, 4), 0, stream, W, PW, wp);

    const int nblocks = 4 * (TT / TILE);   // 2048
    hipLaunchKernelGGL(mcao_main, dim3(nblocks), dim3(256), 0, stream,
                       x, wp, pb, kap, cf, out, memout);
}